// Round 2
// baseline (191.283 us; speedup 1.0000x reference)
//
#include <hip/hip_runtime.h>
#include <stdint.h>

#define NROWS 8192
#define DDIM  128
#define PPART 16
#define JT_PER_PART ((NROWS/16)/PPART)   // 32 column tiles per partition
#define LOG2E_X100 144.26950408889634f   // 100 / ln(2)
#define LN2F       0.6931471805599453f

typedef __bf16 bf16x8 __attribute__((ext_vector_type(8)));
typedef float  f32x4  __attribute__((ext_vector_type(4)));

__device__ __forceinline__ unsigned short f2bf_rne(float f) {
    union { float f; uint32_t u; } v; v.f = f;
    uint32_t r = (v.u + 0x7FFFu + ((v.u >> 16) & 1u)) >> 16;
    return (unsigned short)r;
}

// Kernel 1: fp32 -> bf16. ts pre-scaled by 100*log2(e) so logits are in base-2
// space and the softmax can use raw v_exp_f32. Also zero acc + ticket.
__global__ void convert_kernel(const float* __restrict__ ts, const float* __restrict__ nt,
                               unsigned short* __restrict__ ts_bf,
                               unsigned short* __restrict__ nt_bf,
                               float* __restrict__ acc, int* __restrict__ ticket) {
    const int nvec = (NROWS * DDIM) / 4;
    int tid = blockIdx.x * blockDim.x + threadIdx.x;
    bool isNT = tid >= nvec;
    int i = isNT ? (tid - nvec) : tid;
    const float4 v = ((const float4*)(isNT ? nt : ts))[i];
    float sc = isNT ? 1.0f : LOG2E_X100;
    ushort4 o;
    o.x = f2bf_rne(v.x * sc); o.y = f2bf_rne(v.y * sc);
    o.z = f2bf_rne(v.z * sc); o.w = f2bf_rne(v.w * sc);
    ((ushort4*)(isNT ? nt_bf : ts_bf))[i] = o;
    if (tid == 0) { *acc = 0.0f; *ticket = 0; }
}

// Kernel 2: per-row online-softmax stats over a column partition, base-2 space.
// 1 wave/block, 32 rows/wave (2 strips), j-tiles processed in PAIRS:
// one rescale per pair (1.5 exp/element), 16 MFMAs + 8 B-loads in flight.
// grid = (NROWS/32, PPART, 2 dirs)
__global__ __launch_bounds__(64) void rowstats_kernel(
        const unsigned short* __restrict__ ts_bf,
        const unsigned short* __restrict__ nt_bf,
        float* __restrict__ pm, float* __restrict__ ps, float* __restrict__ pd) {
    const int lane = threadIdx.x;
    const int c    = lane & 15;
    const int quad = lane >> 4;
    const int bx    = blockIdx.x;
    const int rows0 = bx * 32;
    const int part  = blockIdx.y;
    const int dir   = blockIdx.z;

    const unsigned short* A = dir ? nt_bf : ts_bf;
    const unsigned short* B = dir ? ts_bf : nt_bf;

    bf16x8 a[2][4];
#pragma unroll
    for (int s = 0; s < 2; ++s) {
        const unsigned short* abase = A + (rows0 + s * 16 + c) * DDIM + quad * 8;
#pragma unroll
        for (int kc = 0; kc < 4; ++kc)
            a[s][kc] = *(const bf16x8*)(abase + kc * 32);
    }

    float m[2][4], ss[2][4], dg[2][4];
#pragma unroll
    for (int s = 0; s < 2; ++s)
#pragma unroll
        for (int r = 0; r < 4; ++r) { m[s][r] = -INFINITY; ss[s][r] = 0.0f; dg[s][r] = 0.0f; }

    const int jt0 = part * JT_PER_PART;
    const unsigned short* bbase = B + (jt0 * 16 + c) * DDIM + quad * 8;

    for (int t = 0; t < JT_PER_PART / 2; ++t) {
        const int jtA = jt0 + 2 * t;                 // global tile idx, slot A (even)
        const bool pd_ = (jtA == 2 * bx);            // wave-uniform: pair holds both diag tiles

        bf16x8 bA[4], bB[4];
        const unsigned short* pA = bbase + (2 * t) * 16 * DDIM;
        const unsigned short* pB = pA + 16 * DDIM;
#pragma unroll
        for (int kc = 0; kc < 4; ++kc) {
            bA[kc] = *(const bf16x8*)(pA + kc * 32);
            bB[kc] = *(const bf16x8*)(pB + kc * 32);
        }

        f32x4 accA0 = {0,0,0,0}, accA1 = {0,0,0,0}, accB0 = {0,0,0,0}, accB1 = {0,0,0,0};
#pragma unroll
        for (int kc = 0; kc < 4; ++kc) {
            accA0 = __builtin_amdgcn_mfma_f32_16x16x32_bf16(a[0][kc], bA[kc], accA0, 0, 0, 0);
            accA1 = __builtin_amdgcn_mfma_f32_16x16x32_bf16(a[1][kc], bA[kc], accA1, 0, 0, 0);
            accB0 = __builtin_amdgcn_mfma_f32_16x16x32_bf16(a[0][kc], bB[kc], accB0, 0, 0, 0);
            accB1 = __builtin_amdgcn_mfma_f32_16x16x32_bf16(a[1][kc], bB[kc], accB1, 0, 0, 0);
        }

#pragma unroll
        for (int s = 0; s < 2; ++s) {
#pragma unroll
            for (int r = 0; r < 4; ++r) {
                float xA = s ? accA1[r] : accA0[r];
                float xB = s ? accB1[r] : accB0[r];
                if (pd_) {
                    // strip0's diag tile is the even slot (A); strip1's is the odd slot (B)
                    bool onDiag = (c == quad * 4 + r);
                    if (s == 0) { if (onDiag) dg[0][r] += xA; xA = onDiag ? xA : -1.0e30f; }
                    else        { if (onDiag) dg[1][r] += xB; xB = onDiag ? xB : -1.0e30f; }
                }
                float bm = fmaxf(xA, xB);
                float mn = fmaxf(m[s][r], bm);
                ss[s][r] = ss[s][r] * __builtin_amdgcn_exp2f(m[s][r] - mn)
                         + __builtin_amdgcn_exp2f(xA - mn)
                         + __builtin_amdgcn_exp2f(xB - mn);
                m[s][r] = mn;
            }
        }
    }

    // Combine across the 16 lanes of each quad (they share the same 4 rows).
#pragma unroll
    for (int s = 0; s < 2; ++s) {
#pragma unroll
        for (int r = 0; r < 4; ++r) {
            float mm = m[s][r], sv = ss[s][r], dd = dg[s][r];
#pragma unroll
            for (int off = 1; off < 16; off <<= 1) {
                float m2 = __shfl_xor(mm, off, 64);
                float s2 = __shfl_xor(sv, off, 64);
                float d2 = __shfl_xor(dd, off, 64);
                float mn = fmaxf(mm, m2);
                sv = sv * __builtin_amdgcn_exp2f(mm - mn) + s2 * __builtin_amdgcn_exp2f(m2 - mn);
                mm = mn;
                dd += d2;
            }
            if (c == 0) {
                int row = rows0 + s * 16 + quad * 4 + r;
                int idx = (dir * NROWS + row) * PPART + part;
                pm[idx] = mm; ps[idx] = sv; pd[idx] = dd;
            }
        }
    }
}

// Kernel 3: merge partitions per (dir,row), lsm in base-2 -> natural via ln2,
// block-reduce, atomicAdd; last block finalizes the scalar output.
__global__ void merge_kernel(const float* __restrict__ pm, const float* __restrict__ ps,
                             const float* __restrict__ pd, float* __restrict__ acc,
                             int* __restrict__ ticket, float* __restrict__ out) {
    int tid = blockIdx.x * blockDim.x + threadIdx.x;  // 0 .. 2*NROWS-1
    const float* pmr = pm + tid * PPART;
    const float* psr = ps + tid * PPART;
    const float* pdr = pd + tid * PPART;
    float mt = -INFINITY;
#pragma unroll
    for (int p = 0; p < PPART; ++p) mt = fmaxf(mt, pmr[p]);
    float st = 0.0f, dt = 0.0f;
#pragma unroll
    for (int p = 0; p < PPART; ++p) {
        st += psr[p] * __builtin_amdgcn_exp2f(pmr[p] - mt);
        dt += pdr[p];
    }
    float lsm = dt - mt - __builtin_amdgcn_logf(st);   // base-2 log-softmax at diagonal

    float v = lsm;
#pragma unroll
    for (int off = 32; off; off >>= 1) v += __shfl_down(v, off, 64);
    __shared__ float wsum[4];
    if ((threadIdx.x & 63) == 0) wsum[threadIdx.x >> 6] = v;
    __syncthreads();
    if (threadIdx.x == 0) {
        atomicAdd(acc, wsum[0] + wsum[1] + wsum[2] + wsum[3]);
        __threadfence();
        int old = atomicAdd(ticket, 1);
        if (old == (int)gridDim.x - 1) {
            __threadfence();
            float tot = atomicAdd(acc, 0.0f);   // coherent read of final sum
            float t = -(tot * LN2F) / (2.0f * NROWS);
            if (!isfinite(t)) t = 0.0f;
            out[0] = t;
        }
    }
}

extern "C" void kernel_launch(void* const* d_in, const int* in_sizes, int n_in,
                              void* d_out, int out_size, void* d_ws, size_t ws_size,
                              hipStream_t stream) {
    const float* ts = (const float*)d_in[0];
    const float* nt = (const float*)d_in[1];
    float* out = (float*)d_out;

    unsigned short* ts_bf = (unsigned short*)d_ws;                 // 2 MB
    unsigned short* nt_bf = ts_bf + NROWS * DDIM;                  // 2 MB
    float* pm = (float*)(nt_bf + NROWS * DDIM);                    // 1 MB
    float* ps = pm + 2 * NROWS * PPART;                            // 1 MB
    float* pd = ps + 2 * NROWS * PPART;                            // 1 MB
    float* acc = pd + 2 * NROWS * PPART;                           // 4 B
    int* ticket = (int*)(acc + 1);                                 // 4 B

    convert_kernel<<<2048, 256, 0, stream>>>(ts, nt, ts_bf, nt_bf, acc, ticket);
    rowstats_kernel<<<dim3(NROWS / 32, PPART, 2), 64, 0, stream>>>(ts_bf, nt_bf, pm, ps, pd);
    merge_kernel<<<(2 * NROWS) / 256, 256, 0, stream>>>(pm, ps, pd, acc, ticket, out);
}